// Round 5
// baseline (980.363 us; speedup 1.0000x reference)
//
#include <hip/hip_runtime.h>
#include <math.h>

namespace {
constexpr int kB = 16, kV = 30, kNV = 1501, kNE = 2001, kH = 128, kD = 128,
              kL = 2, kOut = 25, kNT = 100000, kE = 800000, kM = kB * kV;
constexpr int kNB = (kNT + 255) / 256;  // 391 scan blocks
constexpr int kKS = 6;                  // split-K factor for logits
constexpr int kKCH = 251;               // ceil(1501/6)
}

// Pn[n][h] = node_emb[n] . lin_w[h] + lin_b[h]
__global__ void pn_kernel(const float* __restrict__ emb, const float* __restrict__ lw,
                          const float* __restrict__ lb, float* __restrict__ pn) {
  int n = blockIdx.x, h = threadIdx.x;
  __shared__ float row[kD];
  row[h] = emb[(size_t)n * kD + h];
  __syncthreads();
  float acc = lb[h];
#pragma unroll 8
  for (int d = 0; d < kD; d++) acc += row[d] * lw[h * kD + d];
  pn[(size_t)n * kH + h] = acc;
}

// x[i] = Pn[cat_node_ids[i]]
__global__ void xinit_kernel(const float4* __restrict__ pn4, const int* __restrict__ nid,
                             float4* __restrict__ x4) {
  int t = blockIdx.x * blockDim.x + threadIdx.x;
  if (t >= kNT * 32) return;
  int i = t >> 5, c = t & 31;
  x4[(size_t)i * 32 + c] = pn4[(size_t)nid[i] * 32 + c];
}

// node branch partials: xacc[b][h] += sum_{n in chunk, ehr[b][n]} PN[n][h]; cnte[b] += cnt
__global__ void xnode_kernel(const int* __restrict__ ehr, const float* __restrict__ pn,
                             float* __restrict__ xacc, int* __restrict__ cnte) {
  int b = blockIdx.x;   // 16
  int c = blockIdx.y;   // 12 chunks of 128 nodes
  int h = threadIdx.x;  // 128
  int n0 = c * 128;
  __shared__ int flags[128];
  int gn = n0 + h;
  flags[h] = (gn < kNV) ? ehr[(size_t)b * kNV + gn] : 0;
  __syncthreads();
  float acc = 0.f;
  int cnt = 0;
  int n1 = min(n0 + 128, kNV);
  for (int n = n0; n < n1; ++n) {
    if (flags[n - n0]) {
      acc += pn[(size_t)n * kH + h];
      cnt++;
    }
  }
  atomicAdd(&xacc[b * kH + h], acc);
  if (h == 0) atomicAdd(&cnte[b], cnt);
}

// u[l][d] = sum_h wr_w[l][h]*lin_w[h][d] ; c[l] = wr_w[l].lin_b + wr_b[l]
__global__ void uc_kernel(const float* __restrict__ wrw, const float* __restrict__ wrb,
                          const float* __restrict__ lw, const float* __restrict__ lb,
                          float* __restrict__ uc) {
  int t = threadIdx.x;  // 256
  int l = t >> 7, d = t & 127;
  float s = 0.f;
  for (int h = 0; h < kH; h++) s += wrw[l * kH + h] * lw[h * kD + d];
  uc[t] = s;
  if (t < kL) {
    float c = wrb[t];
    for (int h = 0; h < kH; h++) c += wrw[t * kH + h] * lb[h];
    uc[256 + t] = c;
  }
}

// wrel[l][r] = sigmoid(edge_emb[r] . u[l] + c[l])
__global__ void wrel_kernel(const float* __restrict__ eemb, const float* __restrict__ uc,
                            float* __restrict__ wrel) {
  int idx = blockIdx.x * blockDim.x + threadIdx.x;
  if (idx >= kL * kNE) return;
  int l = idx / kNE, r = idx % kNE;
  float z = uc[256 + l];
  const float* u = uc + l * 128;
  const float* er = eemb + (size_t)r * kD;
  for (int d = 0; d < kD; d++) z += er[d] * u[d];
  wrel[idx] = 1.f / (1.f + expf(-z));
}

// beta[l][b*V+v] = tanh(vn[b,v,:].beta_w[l] + beta_b[l]) * exp(0.01*(V-v))
__global__ void beta_kernel(const int* __restrict__ vn, const float* __restrict__ bw,
                            const float* __restrict__ bb, float* __restrict__ beta) {
  int blk = blockIdx.x;  // l*kM + r
  int l = blk / kM, r = blk % kM;
  int v = r % kV;
  int lane = threadIdx.x;
  const int* row = vn + (size_t)r * kNV;
  const float* w = bw + (size_t)l * kNV;
  float s = 0.f;
  for (int k = lane; k < kNV; k += 64) s += (float)row[k] * w[k];
  for (int off = 32; off > 0; off >>= 1) s += __shfl_down(s, off, 64);
  if (lane == 0) {
    float lam = expf(0.01f * (float)(kV - v));
    beta[blk] = tanhf(s + bb[l]) * lam;
  }
}

// Partial logits: part[z][r][n] = sum_{k in chunk ks} vn[r][k]*aw[l][n][k], z=l*kKS+ks
// 128x128 tile, 8x8 per thread, K-step 32. Grid (12, 4, kL*kKS=12) = 576 blocks.
__global__ void logits_kernel(const int* __restrict__ vn, const float* __restrict__ aw,
                              float* __restrict__ part) {
  const int z = blockIdx.z;
  const int l = z / kKS, ks = z % kKS;
  const int rb = blockIdx.y * 128;
  const int nb = blockIdx.x * 128;
  const int tid = threadIdx.x;  // 256
  const int kbeg = ks * kKCH;
  const int kend = min(kbeg + kKCH, kNV);
  __shared__ float As[32][132];  // As[k'][m]
  __shared__ float Bs[32][132];  // Bs[k'][n]
  const float* awl = aw + (size_t)l * kNV * kNV;
  const int tx = tid & 15, ty = tid >> 4;
  const int m0 = ty * 8;
  const int n0 = tx * 4;  // cols {n0..n0+3} and {64+n0..64+n0+3}
  float acc[8][8] = {};
  for (int k0 = kbeg; k0 < kend; k0 += 32) {
    __syncthreads();
#pragma unroll
    for (int i = 0; i < 16; ++i) {  // A: 128 m x 32 k (transposed store)
      int idx = tid + i * 256;
      int rr = idx >> 5, cc = idx & 31;
      int gr = rb + rr, gk = k0 + cc;
      As[cc][rr] = (gr < kM && gk < kend) ? (float)vn[(size_t)gr * kNV + gk] : 0.f;
    }
#pragma unroll
    for (int i = 0; i < 16; ++i) {  // B: 128 n x 32 k (transposed store)
      int idx = tid + i * 256;
      int nn = idx >> 5, cc = idx & 31;
      int gn = nb + nn, gk = k0 + cc;
      Bs[cc][nn] = (gn < kNV && gk < kend) ? awl[(size_t)gn * kNV + gk] : 0.f;
    }
    __syncthreads();
#pragma unroll
    for (int d = 0; d < 32; ++d) {
      float4 a0 = *(const float4*)&As[d][m0];
      float4 a1 = *(const float4*)&As[d][m0 + 4];
      float4 b0 = *(const float4*)&Bs[d][n0];
      float4 b1 = *(const float4*)&Bs[d][n0 + 64];
      float am[8] = {a0.x, a0.y, a0.z, a0.w, a1.x, a1.y, a1.z, a1.w};
      float bn[8] = {b0.x, b0.y, b0.z, b0.w, b1.x, b1.y, b1.z, b1.w};
#pragma unroll
      for (int i2 = 0; i2 < 8; ++i2)
#pragma unroll
        for (int j2 = 0; j2 < 8; ++j2) acc[i2][j2] += am[i2] * bn[j2];
    }
  }
  float* P = part + (size_t)z * kM * kNV;
#pragma unroll
  for (int i2 = 0; i2 < 8; ++i2) {
    int r = rb + m0 + i2;
    if (r >= kM) break;
#pragma unroll
    for (int j2 = 0; j2 < 8; ++j2) {
      int n = nb + ((j2 < 4) ? (n0 + j2) : (64 + n0 + j2 - 4));
      if (n < kNV) P[(size_t)r * kNV + n] = acc[i2][j2];
    }
  }
}

// attn[l][b][n] = sum_v softmax_v(sum_ks part + bias) * beta[l][b][v]
__global__ void attn_kernel(const float* __restrict__ part, const float* __restrict__ beta,
                            const float* __restrict__ ab, float* __restrict__ attn) {
  int idx = blockIdx.x * blockDim.x + threadIdx.x;
  if (idx >= kL * kB * kNV) return;
  int n = idx % kNV;
  int lb_ = idx / kNV;  // l*kB + b
  int l = lb_ / kB, b = lb_ % kB;
  size_t o = (size_t)(b * kV) * kNV + n;
  float bias = ab[l * kNV + n];
  float z[kV];
  float m = -1e30f;
#pragma unroll
  for (int v = 0; v < kV; v++) {
    float s = bias;
#pragma unroll
    for (int ks = 0; ks < kKS; ks++)
      s += part[(size_t)(l * kKS + ks) * kM * kNV + o + (size_t)v * kNV];
    z[v] = s;
    m = fmaxf(m, s);
  }
  float s = 0.f, num = 0.f;
  const float* bet = beta + lb_ * kV;
#pragma unroll
  for (int v = 0; v < kV; v++) {
    float e = expf(z[v] - m);
    s += e;
    num += e * bet[v];
  }
  attn[idx] = num / s;
}

// ---- CSR build ----
__global__ void hist_kernel(const int* __restrict__ dst, int* __restrict__ deg) {
  int e = blockIdx.x * blockDim.x + threadIdx.x;
  if (e >= kE) return;
  atomicAdd(&deg[dst[e]], 1);
}

__global__ void scan1_kernel(const int* __restrict__ deg, int* __restrict__ off,
                             int* __restrict__ part) {
  int t = threadIdx.x, i = blockIdx.x * 256 + t;
  int v = (i < kNT) ? deg[i] : 0;
  __shared__ int sm[256];
  sm[t] = v;
  __syncthreads();
  for (int o = 1; o < 256; o <<= 1) {
    int x = (t >= o) ? sm[t - o] : 0;
    __syncthreads();
    sm[t] += x;
    __syncthreads();
  }
  if (i < kNT) off[i] = sm[t] - v;
  if (t == 255) part[blockIdx.x] = sm[255];
}

__global__ void scan2_kernel(int* __restrict__ part) {
  int t = threadIdx.x;  // 512
  int v = (t < kNB) ? part[t] : 0;
  __shared__ int sm[512];
  sm[t] = v;
  __syncthreads();
  for (int o = 1; o < 512; o <<= 1) {
    int x = (t >= o) ? sm[t - o] : 0;
    __syncthreads();
    sm[t] += x;
    __syncthreads();
  }
  if (t < kNB) part[t] = sm[t] - v;
}

__global__ void scan3_kernel(int* __restrict__ off, const int* __restrict__ part,
                             int* __restrict__ cursor) {
  int i = blockIdx.x * 256 + threadIdx.x;
  if (i >= kNT) return;
  int o = off[i] + part[blockIdx.x];
  off[i] = o;
  cursor[i] = o;
}

// scatter edges into CSR slots; precompute per-edge scalars for both layers
__global__ void scatter_kernel(const int* __restrict__ ei, const int* __restrict__ nid,
                               const int* __restrict__ eid, const int* __restrict__ batch,
                               const float* __restrict__ attn, const float* __restrict__ wrel,
                               int* __restrict__ cursor, int* __restrict__ csrc,
                               float* __restrict__ cs0, float* __restrict__ cs1) {
  int e = blockIdx.x * blockDim.x + threadIdx.x;
  if (e >= kE) return;
  int s = ei[e], d = ei[kE + e];
  int b = batch[s], n = nid[s], r = eid[e];
  float a0 = attn[(size_t)b * kNV + n];
  float a1 = attn[(size_t)kB * kNV + b * kNV + n];
  float w0 = wrel[r], w1 = wrel[kNE + r];
  int pos = atomicAdd(&cursor[d], 1);
  csrc[pos] = s;
  cs0[pos] = a0 * w0;
  cs1[pos] = a1 * w1;
}

// rows[n] = x[n] + sum_{edges->n} relu(x[src]*scal)
// 2 nodes per wave, float4 per lane (32 lanes/row), 32-edge register prefetch.
__global__ void gather_kernel(const float* __restrict__ x, const int* __restrict__ csrc,
                              const float* __restrict__ cscal, const int* __restrict__ off,
                              const int* __restrict__ endv, float* __restrict__ rows) {
  int wid = (blockIdx.x * blockDim.x + threadIdx.x) >> 6;
  int lane = threadIdx.x & 63;
  int sub = lane >> 5, sl = lane & 31;
  int node = wid * 2 + sub;
  if (node >= kNT) return;
  const float4* x4 = (const float4*)x;
  float4 acc = x4[(size_t)node * 32 + sl];
  int j0 = off[node], j1 = endv[node];
  for (int base = j0; base < j1; base += 32) {
    int n = j1 - base;
    if (n > 32) n = 32;
    int sidx = 0;
    float ssc = 0.f;
    if (sl < n) {
      sidx = csrc[base + sl];
      ssc = cscal[base + sl];
    }
    for (int t = 0; t < n; ++t) {
      int s = __shfl(sidx, sub * 32 + t, 64);
      float sc = __shfl(ssc, sub * 32 + t, 64);
      float4 xv = x4[(size_t)s * 32 + sl];
      acc.x += fmaxf(xv.x * sc, 0.f);
      acc.y += fmaxf(xv.y * sc, 0.f);
      acc.z += fmaxf(xv.z * sc, 0.f);
      acc.w += fmaxf(xv.w * sc, 0.f);
    }
  }
  ((float4*)rows)[(size_t)node * 32 + sl] = acc;
}

// x_out[n][h] = relu(rows[n] . w[h] + bias[h])
// 128 nodes/block, 8x8 per thread, K-chunks of 32. Grid 782.
__global__ void conv_kernel(const float* __restrict__ rows, const float* __restrict__ w,
                            const float* __restrict__ bias, float* __restrict__ xout) {
  const int nb = blockIdx.x * 128;
  const int tid = threadIdx.x;  // 256
  __shared__ float As[32][132];  // As[d'][node]
  __shared__ float Bs[32][132];  // Bs[d'][h]
  const int tx = tid & 15, ty = tid >> 4;
  const int m0 = ty * 8;
  const int n0 = tx * 4;  // h cols {n0..n0+3} and {64+n0..+3}
  float acc[8][8] = {};
  for (int kc = 0; kc < 4; ++kc) {
    __syncthreads();
#pragma unroll
    for (int i = 0; i < 4; ++i) {  // A: 128 nodes x 32 d via float4
      int fi = tid + i * 256;      // 1024 float4
      int rr = fi >> 3, c4 = (fi & 7) * 4;
      int gr = nb + rr;
      float4 v = (gr < kNT) ? *(const float4*)(rows + (size_t)gr * kD + kc * 32 + c4)
                            : float4{0.f, 0.f, 0.f, 0.f};
      As[c4 + 0][rr] = v.x;
      As[c4 + 1][rr] = v.y;
      As[c4 + 2][rr] = v.z;
      As[c4 + 3][rr] = v.w;
    }
#pragma unroll
    for (int i = 0; i < 4; ++i) {  // B: 128 h x 32 d via float4
      int fi = tid + i * 256;
      int hh = fi >> 3, c4 = (fi & 7) * 4;
      float4 v = *(const float4*)(w + (size_t)hh * kD + kc * 32 + c4);
      Bs[c4 + 0][hh] = v.x;
      Bs[c4 + 1][hh] = v.y;
      Bs[c4 + 2][hh] = v.z;
      Bs[c4 + 3][hh] = v.w;
    }
    __syncthreads();
#pragma unroll
    for (int d = 0; d < 32; ++d) {
      float4 a0 = *(const float4*)&As[d][m0];
      float4 a1 = *(const float4*)&As[d][m0 + 4];
      float4 b0 = *(const float4*)&Bs[d][n0];
      float4 b1 = *(const float4*)&Bs[d][n0 + 64];
      float am[8] = {a0.x, a0.y, a0.z, a0.w, a1.x, a1.y, a1.z, a1.w};
      float bn[8] = {b0.x, b0.y, b0.z, b0.w, b1.x, b1.y, b1.z, b1.w};
#pragma unroll
      for (int i2 = 0; i2 < 8; ++i2)
#pragma unroll
        for (int j2 = 0; j2 < 8; ++j2) acc[i2][j2] += am[i2] * bn[j2];
    }
  }
  float4 bv0 = *(const float4*)(bias + n0);
  float4 bv1 = *(const float4*)(bias + 64 + n0);
#pragma unroll
  for (int i2 = 0; i2 < 8; ++i2) {
    int r = nb + m0 + i2;
    if (r >= kNT) break;
    float4 o0, o1;
    o0.x = fmaxf(acc[i2][0] + bv0.x, 0.f);
    o0.y = fmaxf(acc[i2][1] + bv0.y, 0.f);
    o0.z = fmaxf(acc[i2][2] + bv0.z, 0.f);
    o0.w = fmaxf(acc[i2][3] + bv0.w, 0.f);
    o1.x = fmaxf(acc[i2][4] + bv1.x, 0.f);
    o1.y = fmaxf(acc[i2][5] + bv1.y, 0.f);
    o1.z = fmaxf(acc[i2][6] + bv1.z, 0.f);
    o1.w = fmaxf(acc[i2][7] + bv1.w, 0.f);
    *(float4*)(xout + (size_t)r * kH + n0) = o0;
    *(float4*)(xout + (size_t)r * kH + 64 + n0) = o1;
  }
}

// mean-pool: register accumulation with flush-on-batch-change (correct for any batch array)
__global__ void pool_kernel(const float* __restrict__ x, const int* __restrict__ batch,
                            float* __restrict__ xg, int* __restrict__ cnt) {
  int h = threadIdx.x;  // 128
  int start = blockIdx.x * 256;
  int end = start + 256;
  if (end > kNT) end = kNT;
  int cur = batch[start];
  float acc = 0.f;
  int c = 0;
  for (int i = start; i < end; i++) {
    int bb = batch[i];
    if (bb != cur) {
      atomicAdd(&xg[cur * kH + h], acc);
      if (h == 0) atomicAdd(&cnt[cur], c);
      acc = 0.f;
      c = 0;
      cur = bb;
    }
    acc += x[(size_t)i * kH + h];
    c++;
  }
  atomicAdd(&xg[cur * kH + h], acc);
  if (h == 0) atomicAdd(&cnt[cur], c);
}

// out[b][o] = concat(xg[b]/cnt[b], xacc[b]/cnte[b]) . mlp_w[o] + mlp_b[o]
__global__ void final_kernel(const float* __restrict__ xg, const int* __restrict__ cnt,
                             const float* __restrict__ xacc, const int* __restrict__ cnte,
                             const float* __restrict__ mw, const float* __restrict__ mb,
                             float* __restrict__ out) {
  int idx = blockIdx.x * blockDim.x + threadIdx.x;
  if (idx >= kB * kOut) return;
  int b = idx / kOut, o = idx % kOut;
  float invg = 1.f / (float)cnt[b];
  float invn = 1.f / (float)cnte[b];
  float acc = mb[o];
  const float* w = mw + (size_t)o * (2 * kH);
  for (int h = 0; h < kH; h++) acc += xg[b * kH + h] * invg * w[h];
  for (int h = 0; h < kH; h++) acc += xacc[b * kH + h] * invn * w[kH + h];
  out[idx] = acc;
}

extern "C" void kernel_launch(void* const* d_in, const int* in_sizes, int n_in,
                              void* d_out, int out_size, void* d_ws, size_t ws_size,
                              hipStream_t stream) {
  const float* node_emb = (const float*)d_in[0];
  const float* edge_emb = (const float*)d_in[1];
  const float* lin_w = (const float*)d_in[2];
  const float* lin_b = (const float*)d_in[3];
  const float* alpha_w = (const float*)d_in[4];
  const float* alpha_b = (const float*)d_in[5];
  const float* beta_w = (const float*)d_in[6];
  const float* beta_b = (const float*)d_in[7];
  const float* wr_w = (const float*)d_in[8];
  const float* wr_b = (const float*)d_in[9];
  const float* conv_w = (const float*)d_in[10];
  const float* conv_b = (const float*)d_in[11];
  const float* mlp_w = (const float*)d_in[12];
  const float* mlp_b = (const float*)d_in[13];
  const int* visit_node = (const int*)d_in[14];
  const int* ehr_nodes = (const int*)d_in[15];
  const int* cat_node_ids = (const int*)d_in[16];
  const int* cat_edge_ids = (const int*)d_in[17];
  const int* edge_index = (const int*)d_in[18];
  const int* batch = (const int*)d_in[19];

  char* ws = (char*)d_ws;
  float* X = (float*)(ws);                            // 51,200,000
  float* ROWS = (float*)(ws + 51200000);              // 51,200,000
  float* PN = ROWS;                                   // alias (dead before ROWS used)
  float* LPART = (float*)(ws + 51200000 + 786432);    // 34,583,040 (alias in ROWS)
  float* ATTN = (float*)(ws + 102400000);             // 192,128
  float* BETA = (float*)(ws + 102592256);             // 3,840
  float* UC = (float*)(ws + 102596352);               // 1,032
  float* WREL = (float*)(ws + 102597632);             // 16,008
  int* OFF = (int*)(ws + 102613760);                  // 400,004
  int* CURSOR = (int*)(ws + 103014016);               // 400,000 (also DEG)
  int* SPART = (int*)(ws + 103414016);                // 2,048
  int* CSRS = (int*)(ws + 103416064);                 // 3,200,000
  float* CS0 = (float*)(ws + 106616064);              // 3,200,000
  float* CS1 = (float*)(ws + 109816064);              // 3,200,000
  float* XG = (float*)(ws + 113016064);               // 8,192
  int* CNT = (int*)(ws + 113024256);                  // 64
  float* XNACC = (float*)(ws + 113024320);            // 8,192
  int* CNTE = (int*)(ws + 113032512);                 // 64

  pn_kernel<<<kNV, kH, 0, stream>>>(node_emb, lin_w, lin_b, PN);
  xinit_kernel<<<(kNT * 32 + 255) / 256, 256, 0, stream>>>((const float4*)PN, cat_node_ids,
                                                           (float4*)X);
  // zero XG + CNT + XNACC + CNTE (contiguous 16,512 B)
  hipMemsetAsync(XG, 0, 16512, stream);
  xnode_kernel<<<dim3(kB, 12), kH, 0, stream>>>(ehr_nodes, PN, XNACC, CNTE);
  uc_kernel<<<1, 256, 0, stream>>>(wr_w, wr_b, lin_w, lin_b, UC);
  wrel_kernel<<<(kL * kNE + 255) / 256, 256, 0, stream>>>(edge_emb, UC, WREL);
  beta_kernel<<<kL * kM, 64, 0, stream>>>(visit_node, beta_w, beta_b, BETA);
  logits_kernel<<<dim3((kNV + 127) / 128, (kM + 127) / 128, kL * kKS), 256, 0, stream>>>(
      visit_node, alpha_w, LPART);
  attn_kernel<<<(kL * kB * kNV + 255) / 256, 256, 0, stream>>>(LPART, BETA, alpha_b, ATTN);

  const int* dst = edge_index + kE;
  hipMemsetAsync(CURSOR, 0, kNT * 4, stream);
  hist_kernel<<<(kE + 255) / 256, 256, 0, stream>>>(dst, CURSOR);
  scan1_kernel<<<kNB, 256, 0, stream>>>(CURSOR, OFF, SPART);
  scan2_kernel<<<1, 512, 0, stream>>>(SPART);
  scan3_kernel<<<kNB, 256, 0, stream>>>(OFF, SPART, CURSOR);
  scatter_kernel<<<(kE + 255) / 256, 256, 0, stream>>>(edge_index, cat_node_ids, cat_edge_ids,
                                                       batch, ATTN, WREL, CURSOR, CSRS, CS0, CS1);

  for (int l = 0; l < kL; l++) {
    gather_kernel<<<kNT / 8, 256, 0, stream>>>(X, CSRS, (l ? CS1 : CS0), OFF, CURSOR, ROWS);
    conv_kernel<<<(kNT + 127) / 128, 256, 0, stream>>>(ROWS, conv_w + (size_t)l * kH * kD,
                                                       conv_b + (size_t)l * kH, X);
  }

  pool_kernel<<<(kNT + 255) / 256, kH, 0, stream>>>(X, batch, XG, CNT);
  final_kernel<<<2, 256, 0, stream>>>(XG, CNT, XNACC, CNTE, mlp_w, mlp_b, (float*)d_out);
}

// Round 6
// 880.199 us; speedup vs baseline: 1.1138x; 1.1138x over previous
//
#include <hip/hip_runtime.h>
#include <math.h>

namespace {
constexpr int kB = 16, kV = 30, kNV = 1501, kNE = 2001, kH = 128, kD = 128,
              kL = 2, kOut = 25, kNT = 100000, kE = 800000, kM = kB * kV;
constexpr int kNB = (kNT + 255) / 256;  // 391 scan blocks
}

// Pn[n][h] = node_emb[n] . lin_w[h] + lin_b[h]
__global__ void pn_kernel(const float* __restrict__ emb, const float* __restrict__ lw,
                          const float* __restrict__ lb, float* __restrict__ pn) {
  int n = blockIdx.x, h = threadIdx.x;
  __shared__ float row[kD];
  row[h] = emb[(size_t)n * kD + h];
  __syncthreads();
  float acc = lb[h];
#pragma unroll 8
  for (int d = 0; d < kD; d++) acc += row[d] * lw[h * kD + d];
  pn[(size_t)n * kH + h] = acc;
}

// x[i] = Pn[cat_node_ids[i]]
__global__ void xinit_kernel(const float4* __restrict__ pn4, const int* __restrict__ nid,
                             float4* __restrict__ x4) {
  int t = blockIdx.x * blockDim.x + threadIdx.x;
  if (t >= kNT * 32) return;
  int i = t >> 5, c = t & 31;
  x4[(size_t)i * 32 + c] = pn4[(size_t)nid[i] * 32 + c];
}

// node branch partials: xacc[b][h] += sum_{n in chunk, ehr[b][n]} PN[n][h]; cnte[b] += cnt
__global__ void xnode_kernel(const int* __restrict__ ehr, const float* __restrict__ pn,
                             float* __restrict__ xacc, int* __restrict__ cnte) {
  int b = blockIdx.x;   // 16
  int c = blockIdx.y;   // 12 chunks of 128 nodes
  int h = threadIdx.x;  // 128
  int n0 = c * 128;
  __shared__ int flags[128];
  int gn = n0 + h;
  flags[h] = (gn < kNV) ? ehr[(size_t)b * kNV + gn] : 0;
  __syncthreads();
  float acc = 0.f;
  int cnt = 0;
  int n1 = min(n0 + 128, kNV);
  for (int n = n0; n < n1; ++n) {
    if (flags[n - n0]) {
      acc += pn[(size_t)n * kH + h];
      cnt++;
    }
  }
  atomicAdd(&xacc[b * kH + h], acc);
  if (h == 0) atomicAdd(&cnte[b], cnt);
}

// u[l][d] = sum_h wr_w[l][h]*lin_w[h][d] ; c[l] = wr_w[l].lin_b + wr_b[l]
__global__ void uc_kernel(const float* __restrict__ wrw, const float* __restrict__ wrb,
                          const float* __restrict__ lw, const float* __restrict__ lb,
                          float* __restrict__ uc) {
  int t = threadIdx.x;  // 256
  int l = t >> 7, d = t & 127;
  float s = 0.f;
  for (int h = 0; h < kH; h++) s += wrw[l * kH + h] * lw[h * kD + d];
  uc[t] = s;
  if (t < kL) {
    float c = wrb[t];
    for (int h = 0; h < kH; h++) c += wrw[t * kH + h] * lb[h];
    uc[256 + t] = c;
  }
}

// wrel[l][r] = sigmoid(edge_emb[r] . u[l] + c[l])
__global__ void wrel_kernel(const float* __restrict__ eemb, const float* __restrict__ uc,
                            float* __restrict__ wrel) {
  int idx = blockIdx.x * blockDim.x + threadIdx.x;
  if (idx >= kL * kNE) return;
  int l = idx / kNE, r = idx % kNE;
  float z = uc[256 + l];
  const float* u = uc + l * 128;
  const float* er = eemb + (size_t)r * kD;
  for (int d = 0; d < kD; d++) z += er[d] * u[d];
  wrel[idx] = 1.f / (1.f + expf(-z));
}

// beta[l][b*V+v] = tanh(vn[b,v,:].beta_w[l] + beta_b[l]) * exp(0.01*(V-v))
__global__ void beta_kernel(const int* __restrict__ vn, const float* __restrict__ bw,
                            const float* __restrict__ bb, float* __restrict__ beta) {
  int blk = blockIdx.x;  // l*kM + r
  int l = blk / kM, r = blk % kM;
  int v = r % kV;
  int lane = threadIdx.x;
  const int* row = vn + (size_t)r * kNV;
  const float* w = bw + (size_t)l * kNV;
  float s = 0.f;
  for (int k = lane; k < kNV; k += 64) s += (float)row[k] * w[k];
  for (int off = 32; off > 0; off >>= 1) s += __shfl_down(s, off, 64);
  if (lane == 0) {
    float lam = expf(0.01f * (float)(kV - v));
    beta[blk] = tanhf(s + bb[l]) * lam;
  }
}

// Fused visit-attention: for block (l, b, 128-col n-tile):
//   z[v][n] = sum_k vn[b,v,k] * aw[l][n][k]   (alpha_b dropped: constant over v,
//   cancels in softmax)
//   attn[l][b][n] = sum_v softmax_v(z) * beta[l][b][v]
// 256 threads, thread = (n-quad, v-quad), acc[4][4]. No global intermediates.
__global__ void fused_attn_kernel(const int* __restrict__ vn, const float* __restrict__ aw,
                                  const float* __restrict__ beta, float* __restrict__ attn) {
  const int l = blockIdx.z, b = blockIdx.y;
  const int nb = blockIdx.x * 128;
  const int tid = threadIdx.x;  // 256
  __shared__ float Bs[32][136];   // Bs[k'][n]
  __shared__ float VsT[32][36];   // VsT[k'][v]
  __shared__ float Z[kV][132];    // z[v][n] for epilogue
  const float* awl = aw + (size_t)l * kNV * kNV;
  const int* vnb = vn + (size_t)(b * kV) * kNV;
  const int nc4 = (tid & 31) * 4;
  const int vg4 = (tid >> 5) * 4;
  float acc[4][4] = {};
  for (int k0 = 0; k0 < kNV; k0 += 32) {
    __syncthreads();
#pragma unroll
    for (int i = 0; i < 16; ++i) {  // aw tile: 128 n x 32 k, store k-major
      int e = tid + i * 256;
      int nn = e >> 5, kk = e & 31;
      int gn = nb + nn, gk = k0 + kk;
      Bs[kk][nn] = (gn < kNV && gk < kNV) ? awl[(size_t)gn * kNV + gk] : 0.f;
    }
#pragma unroll
    for (int i = 0; i < 4; ++i) {  // vn chunk: 30 v x 32 k, transposed
      int e = tid + i * 256;
      if (e < kV * 32) {
        int v = e >> 5, kk = e & 31;
        int gk = k0 + kk;
        VsT[kk][v] = (gk < kNV) ? (float)vnb[(size_t)v * kNV + gk] : 0.f;
      }
    }
    __syncthreads();
#pragma unroll 8
    for (int kk = 0; kk < 32; ++kk) {
      float4 bv = *(const float4*)&Bs[kk][nc4];
      float4 vv = *(const float4*)&VsT[kk][vg4];
      acc[0][0] += vv.x * bv.x; acc[0][1] += vv.x * bv.y; acc[0][2] += vv.x * bv.z; acc[0][3] += vv.x * bv.w;
      acc[1][0] += vv.y * bv.x; acc[1][1] += vv.y * bv.y; acc[1][2] += vv.y * bv.z; acc[1][3] += vv.y * bv.w;
      acc[2][0] += vv.z * bv.x; acc[2][1] += vv.z * bv.y; acc[2][2] += vv.z * bv.z; acc[2][3] += vv.z * bv.w;
      acc[3][0] += vv.w * bv.x; acc[3][1] += vv.w * bv.y; acc[3][2] += vv.w * bv.z; acc[3][3] += vv.w * bv.w;
    }
  }
  __syncthreads();
#pragma unroll
  for (int i = 0; i < 4; ++i) {
    int v = vg4 + i;
    if (v < kV) {
      Z[v][nc4 + 0] = acc[i][0];
      Z[v][nc4 + 1] = acc[i][1];
      Z[v][nc4 + 2] = acc[i][2];
      Z[v][nc4 + 3] = acc[i][3];
    }
  }
  __syncthreads();
  if (tid < 128) {
    int n = nb + tid;
    if (n < kNV) {
      float zz[kV];
      float m = -1e30f;
#pragma unroll
      for (int v = 0; v < kV; ++v) {
        zz[v] = Z[v][tid];
        m = fmaxf(m, zz[v]);
      }
      const float* bet = beta + (size_t)l * kM + b * kV;
      float s = 0.f, num = 0.f;
#pragma unroll
      for (int v = 0; v < kV; ++v) {
        float e = expf(zz[v] - m);
        s += e;
        num += e * bet[v];
      }
      attn[(size_t)(l * kB + b) * kNV + n] = num / s;
    }
  }
}

// ---- CSR build ----
__global__ void hist_kernel(const int* __restrict__ dst, int* __restrict__ deg) {
  int e = blockIdx.x * blockDim.x + threadIdx.x;
  if (e >= kE) return;
  atomicAdd(&deg[dst[e]], 1);
}

__global__ void scan1_kernel(const int* __restrict__ deg, int* __restrict__ off,
                             int* __restrict__ part) {
  int t = threadIdx.x, i = blockIdx.x * 256 + t;
  int v = (i < kNT) ? deg[i] : 0;
  __shared__ int sm[256];
  sm[t] = v;
  __syncthreads();
  for (int o = 1; o < 256; o <<= 1) {
    int x = (t >= o) ? sm[t - o] : 0;
    __syncthreads();
    sm[t] += x;
    __syncthreads();
  }
  if (i < kNT) off[i] = sm[t] - v;
  if (t == 255) part[blockIdx.x] = sm[255];
}

__global__ void scan2_kernel(int* __restrict__ part) {
  int t = threadIdx.x;  // 512
  int v = (t < kNB) ? part[t] : 0;
  __shared__ int sm[512];
  sm[t] = v;
  __syncthreads();
  for (int o = 1; o < 512; o <<= 1) {
    int x = (t >= o) ? sm[t - o] : 0;
    __syncthreads();
    sm[t] += x;
    __syncthreads();
  }
  if (t < kNB) part[t] = sm[t] - v;
}

__global__ void scan3_kernel(int* __restrict__ off, const int* __restrict__ part,
                             int* __restrict__ cursor) {
  int i = blockIdx.x * 256 + threadIdx.x;
  if (i >= kNT) return;
  int o = off[i] + part[blockIdx.x];
  off[i] = o;
  cursor[i] = o;
}

// scatter edges into CSR slots; precompute per-edge scalars for both layers
__global__ void scatter_kernel(const int* __restrict__ ei, const int* __restrict__ nid,
                               const int* __restrict__ eid, const int* __restrict__ batch,
                               const float* __restrict__ attn, const float* __restrict__ wrel,
                               int* __restrict__ cursor, int* __restrict__ csrc,
                               float* __restrict__ cs0, float* __restrict__ cs1) {
  int e = blockIdx.x * blockDim.x + threadIdx.x;
  if (e >= kE) return;
  int s = ei[e], d = ei[kE + e];
  int b = batch[s], n = nid[s], r = eid[e];
  float a0 = attn[(size_t)b * kNV + n];
  float a1 = attn[(size_t)kB * kNV + b * kNV + n];
  float w0 = wrel[r], w1 = wrel[kNE + r];
  int pos = atomicAdd(&cursor[d], 1);
  csrc[pos] = s;
  cs0[pos] = a0 * w0;
  cs1[pos] = a1 * w1;
}

// rows[n] = x[n] + sum_{edges->n} relu(x[src]*scal)
// 2 nodes per wave, float4 per lane (32 lanes/row), 32-edge register prefetch.
__global__ void gather_kernel(const float* __restrict__ x, const int* __restrict__ csrc,
                              const float* __restrict__ cscal, const int* __restrict__ off,
                              const int* __restrict__ endv, float* __restrict__ rows) {
  int wid = (blockIdx.x * blockDim.x + threadIdx.x) >> 6;
  int lane = threadIdx.x & 63;
  int sub = lane >> 5, sl = lane & 31;
  int node = wid * 2 + sub;
  if (node >= kNT) return;
  const float4* x4 = (const float4*)x;
  float4 acc = x4[(size_t)node * 32 + sl];
  int j0 = off[node], j1 = endv[node];
  for (int base = j0; base < j1; base += 32) {
    int n = j1 - base;
    if (n > 32) n = 32;
    int sidx = 0;
    float ssc = 0.f;
    if (sl < n) {
      sidx = csrc[base + sl];
      ssc = cscal[base + sl];
    }
    for (int t = 0; t < n; ++t) {
      int s = __shfl(sidx, sub * 32 + t, 64);
      float sc = __shfl(ssc, sub * 32 + t, 64);
      float4 xv = x4[(size_t)s * 32 + sl];
      acc.x += fmaxf(xv.x * sc, 0.f);
      acc.y += fmaxf(xv.y * sc, 0.f);
      acc.z += fmaxf(xv.z * sc, 0.f);
      acc.w += fmaxf(xv.w * sc, 0.f);
    }
  }
  ((float4*)rows)[(size_t)node * 32 + sl] = acc;
}

// x_out[n][h] = relu(rows[n] . w[h] + bias[h])
// 128 nodes/block, 8x8 per thread, K-chunks of 32. Grid 782.
__global__ void conv_kernel(const float* __restrict__ rows, const float* __restrict__ w,
                            const float* __restrict__ bias, float* __restrict__ xout) {
  const int nb = blockIdx.x * 128;
  const int tid = threadIdx.x;  // 256
  __shared__ float As[32][132];  // As[d'][node]
  __shared__ float Bs[32][132];  // Bs[d'][h]
  const int tx = tid & 15, ty = tid >> 4;
  const int m0 = ty * 8;
  const int n0 = tx * 4;  // h cols {n0..n0+3} and {64+n0..+3}
  float acc[8][8] = {};
  for (int kc = 0; kc < 4; ++kc) {
    __syncthreads();
#pragma unroll
    for (int i = 0; i < 4; ++i) {  // A: 128 nodes x 32 d via float4
      int fi = tid + i * 256;      // 1024 float4
      int rr = fi >> 3, c4 = (fi & 7) * 4;
      int gr = nb + rr;
      float4 v = (gr < kNT) ? *(const float4*)(rows + (size_t)gr * kD + kc * 32 + c4)
                            : float4{0.f, 0.f, 0.f, 0.f};
      As[c4 + 0][rr] = v.x;
      As[c4 + 1][rr] = v.y;
      As[c4 + 2][rr] = v.z;
      As[c4 + 3][rr] = v.w;
    }
#pragma unroll
    for (int i = 0; i < 4; ++i) {  // B: 128 h x 32 d via float4
      int fi = tid + i * 256;
      int hh = fi >> 3, c4 = (fi & 7) * 4;
      float4 v = *(const float4*)(w + (size_t)hh * kD + kc * 32 + c4);
      Bs[c4 + 0][hh] = v.x;
      Bs[c4 + 1][hh] = v.y;
      Bs[c4 + 2][hh] = v.z;
      Bs[c4 + 3][hh] = v.w;
    }
    __syncthreads();
#pragma unroll
    for (int d = 0; d < 32; ++d) {
      float4 a0 = *(const float4*)&As[d][m0];
      float4 a1 = *(const float4*)&As[d][m0 + 4];
      float4 b0 = *(const float4*)&Bs[d][n0];
      float4 b1 = *(const float4*)&Bs[d][n0 + 64];
      float am[8] = {a0.x, a0.y, a0.z, a0.w, a1.x, a1.y, a1.z, a1.w};
      float bn[8] = {b0.x, b0.y, b0.z, b0.w, b1.x, b1.y, b1.z, b1.w};
#pragma unroll
      for (int i2 = 0; i2 < 8; ++i2)
#pragma unroll
        for (int j2 = 0; j2 < 8; ++j2) acc[i2][j2] += am[i2] * bn[j2];
    }
  }
  float4 bv0 = *(const float4*)(bias + n0);
  float4 bv1 = *(const float4*)(bias + 64 + n0);
#pragma unroll
  for (int i2 = 0; i2 < 8; ++i2) {
    int r = nb + m0 + i2;
    if (r >= kNT) break;
    float4 o0, o1;
    o0.x = fmaxf(acc[i2][0] + bv0.x, 0.f);
    o0.y = fmaxf(acc[i2][1] + bv0.y, 0.f);
    o0.z = fmaxf(acc[i2][2] + bv0.z, 0.f);
    o0.w = fmaxf(acc[i2][3] + bv0.w, 0.f);
    o1.x = fmaxf(acc[i2][4] + bv1.x, 0.f);
    o1.y = fmaxf(acc[i2][5] + bv1.y, 0.f);
    o1.z = fmaxf(acc[i2][6] + bv1.z, 0.f);
    o1.w = fmaxf(acc[i2][7] + bv1.w, 0.f);
    *(float4*)(xout + (size_t)r * kH + n0) = o0;
    *(float4*)(xout + (size_t)r * kH + 64 + n0) = o1;
  }
}

// mean-pool: register accumulation with flush-on-batch-change (correct for any batch array)
__global__ void pool_kernel(const float* __restrict__ x, const int* __restrict__ batch,
                            float* __restrict__ xg, int* __restrict__ cnt) {
  int h = threadIdx.x;  // 128
  int start = blockIdx.x * 256;
  int end = start + 256;
  if (end > kNT) end = kNT;
  int cur = batch[start];
  float acc = 0.f;
  int c = 0;
  for (int i = start; i < end; i++) {
    int bb = batch[i];
    if (bb != cur) {
      atomicAdd(&xg[cur * kH + h], acc);
      if (h == 0) atomicAdd(&cnt[cur], c);
      acc = 0.f;
      c = 0;
      cur = bb;
    }
    acc += x[(size_t)i * kH + h];
    c++;
  }
  atomicAdd(&xg[cur * kH + h], acc);
  if (h == 0) atomicAdd(&cnt[cur], c);
}

// out[b][o] = concat(xg[b]/cnt[b], xacc[b]/cnte[b]) . mlp_w[o] + mlp_b[o]
__global__ void final_kernel(const float* __restrict__ xg, const int* __restrict__ cnt,
                             const float* __restrict__ xacc, const int* __restrict__ cnte,
                             const float* __restrict__ mw, const float* __restrict__ mb,
                             float* __restrict__ out) {
  int idx = blockIdx.x * blockDim.x + threadIdx.x;
  if (idx >= kB * kOut) return;
  int b = idx / kOut, o = idx % kOut;
  float invg = 1.f / (float)cnt[b];
  float invn = 1.f / (float)cnte[b];
  float acc = mb[o];
  const float* w = mw + (size_t)o * (2 * kH);
  for (int h = 0; h < kH; h++) acc += xg[b * kH + h] * invg * w[h];
  for (int h = 0; h < kH; h++) acc += xacc[b * kH + h] * invn * w[kH + h];
  out[idx] = acc;
}

extern "C" void kernel_launch(void* const* d_in, const int* in_sizes, int n_in,
                              void* d_out, int out_size, void* d_ws, size_t ws_size,
                              hipStream_t stream) {
  const float* node_emb = (const float*)d_in[0];
  const float* edge_emb = (const float*)d_in[1];
  const float* lin_w = (const float*)d_in[2];
  const float* lin_b = (const float*)d_in[3];
  const float* alpha_w = (const float*)d_in[4];
  const float* alpha_b = (const float*)d_in[5];
  const float* beta_w = (const float*)d_in[6];
  const float* beta_b = (const float*)d_in[7];
  const float* wr_w = (const float*)d_in[8];
  const float* wr_b = (const float*)d_in[9];
  const float* conv_w = (const float*)d_in[10];
  const float* conv_b = (const float*)d_in[11];
  const float* mlp_w = (const float*)d_in[12];
  const float* mlp_b = (const float*)d_in[13];
  const int* visit_node = (const int*)d_in[14];
  const int* ehr_nodes = (const int*)d_in[15];
  const int* cat_node_ids = (const int*)d_in[16];
  const int* cat_edge_ids = (const int*)d_in[17];
  const int* edge_index = (const int*)d_in[18];
  const int* batch = (const int*)d_in[19];

  char* ws = (char*)d_ws;
  float* X = (float*)(ws);                            // 51,200,000
  float* ROWS = (float*)(ws + 51200000);              // 51,200,000
  float* PN = ROWS;                                   // alias (dead before ROWS used)
  float* ATTN = (float*)(ws + 102400000);             // 192,128
  float* BETA = (float*)(ws + 102592256);             // 3,840
  float* UC = (float*)(ws + 102596352);               // 1,032
  float* WREL = (float*)(ws + 102597632);             // 16,008
  int* OFF = (int*)(ws + 102613760);                  // 400,004
  int* CURSOR = (int*)(ws + 103014016);               // 400,000 (also DEG)
  int* SPART = (int*)(ws + 103414016);                // 2,048
  int* CSRS = (int*)(ws + 103416064);                 // 3,200,000
  float* CS0 = (float*)(ws + 106616064);              // 3,200,000
  float* CS1 = (float*)(ws + 109816064);              // 3,200,000
  float* XG = (float*)(ws + 113016064);               // 8,192
  int* CNT = (int*)(ws + 113024256);                  // 64
  float* XNACC = (float*)(ws + 113024320);            // 8,192
  int* CNTE = (int*)(ws + 113032512);                 // 64

  pn_kernel<<<kNV, kH, 0, stream>>>(node_emb, lin_w, lin_b, PN);
  xinit_kernel<<<(kNT * 32 + 255) / 256, 256, 0, stream>>>((const float4*)PN, cat_node_ids,
                                                           (float4*)X);
  // zero XG + CNT + XNACC + CNTE (contiguous 16,512 B)
  hipMemsetAsync(XG, 0, 16512, stream);
  xnode_kernel<<<dim3(kB, 12), kH, 0, stream>>>(ehr_nodes, PN, XNACC, CNTE);
  uc_kernel<<<1, 256, 0, stream>>>(wr_w, wr_b, lin_w, lin_b, UC);
  wrel_kernel<<<(kL * kNE + 255) / 256, 256, 0, stream>>>(edge_emb, UC, WREL);
  beta_kernel<<<kL * kM, 64, 0, stream>>>(visit_node, beta_w, beta_b, BETA);
  fused_attn_kernel<<<dim3((kNV + 127) / 128, kB, kL), 256, 0, stream>>>(visit_node, alpha_w,
                                                                         BETA, ATTN);

  const int* dst = edge_index + kE;
  hipMemsetAsync(CURSOR, 0, kNT * 4, stream);
  hist_kernel<<<(kE + 255) / 256, 256, 0, stream>>>(dst, CURSOR);
  scan1_kernel<<<kNB, 256, 0, stream>>>(CURSOR, OFF, SPART);
  scan2_kernel<<<1, 512, 0, stream>>>(SPART);
  scan3_kernel<<<kNB, 256, 0, stream>>>(OFF, SPART, CURSOR);
  scatter_kernel<<<(kE + 255) / 256, 256, 0, stream>>>(edge_index, cat_node_ids, cat_edge_ids,
                                                       batch, ATTN, WREL, CURSOR, CSRS, CS0, CS1);

  for (int l = 0; l < kL; l++) {
    gather_kernel<<<kNT / 8, 256, 0, stream>>>(X, CSRS, (l ? CS1 : CS0), OFF, CURSOR, ROWS);
    conv_kernel<<<(kNT + 127) / 128, 256, 0, stream>>>(ROWS, conv_w + (size_t)l * kH * kD,
                                                       conv_b + (size_t)l * kH, X);
  }

  pool_kernel<<<(kNT + 255) / 256, kH, 0, stream>>>(X, batch, XG, CNT);
  final_kernel<<<2, 256, 0, stream>>>(XG, CNT, XNACC, CNTE, mlp_w, mlp_b, (float*)d_out);
}

// Round 7
// 708.255 us; speedup vs baseline: 1.3842x; 1.2428x over previous
//
#include <hip/hip_runtime.h>
#include <math.h>

namespace {
constexpr int kB = 16, kV = 30, kNV = 1501, kNE = 2001, kH = 128, kD = 128,
              kL = 2, kOut = 25, kNT = 100000, kE = 800000, kM = kB * kV;
constexpr int kNB = (kNT + 255) / 256;  // 391 scan blocks
constexpr int kKT = 47;                 // k-chunks of 32 (47*32 = 1504 >= 1501)
constexpr int kKP = kKT * 32;           // padded K = 1504
}

// Pn[n][h] = node_emb[n] . lin_w[h] + lin_b[h]
__global__ void pn_kernel(const float* __restrict__ emb, const float* __restrict__ lw,
                          const float* __restrict__ lb, float* __restrict__ pn) {
  int n = blockIdx.x, h = threadIdx.x;
  __shared__ float row[kD];
  row[h] = emb[(size_t)n * kD + h];
  __syncthreads();
  float acc = lb[h];
#pragma unroll 8
  for (int d = 0; d < kD; d++) acc += row[d] * lw[h * kD + d];
  pn[(size_t)n * kH + h] = acc;
}

// x[i] = Pn[cat_node_ids[i]]
__global__ void xinit_kernel(const float4* __restrict__ pn4, const int* __restrict__ nid,
                             float4* __restrict__ x4) {
  int t = blockIdx.x * blockDim.x + threadIdx.x;
  if (t >= kNT * 32) return;
  int i = t >> 5, c = t & 31;
  x4[(size_t)i * 32 + c] = pn4[(size_t)nid[i] * 32 + c];
}

// node branch partials
__global__ void xnode_kernel(const int* __restrict__ ehr, const float* __restrict__ pn,
                             float* __restrict__ xacc, int* __restrict__ cnte) {
  int b = blockIdx.x;
  int c = blockIdx.y;
  int h = threadIdx.x;
  int n0 = c * 128;
  __shared__ int flags[128];
  int gn = n0 + h;
  flags[h] = (gn < kNV) ? ehr[(size_t)b * kNV + gn] : 0;
  __syncthreads();
  float acc = 0.f;
  int cnt = 0;
  int n1 = min(n0 + 128, kNV);
  for (int n = n0; n < n1; ++n) {
    if (flags[n - n0]) {
      acc += pn[(size_t)n * kH + h];
      cnt++;
    }
  }
  atomicAdd(&xacc[b * kH + h], acc);
  if (h == 0) atomicAdd(&cnte[b], cnt);
}

// u[l][d] = sum_h wr_w[l][h]*lin_w[h][d] ; c[l] = wr_w[l].lin_b + wr_b[l]
__global__ void uc_kernel(const float* __restrict__ wrw, const float* __restrict__ wrb,
                          const float* __restrict__ lw, const float* __restrict__ lb,
                          float* __restrict__ uc) {
  int t = threadIdx.x;
  int l = t >> 7, d = t & 127;
  float s = 0.f;
  for (int h = 0; h < kH; h++) s += wrw[l * kH + h] * lw[h * kD + d];
  uc[t] = s;
  if (t < kL) {
    float c = wrb[t];
    for (int h = 0; h < kH; h++) c += wrw[t * kH + h] * lb[h];
    uc[256 + t] = c;
  }
}

// wrel[l][r] = sigmoid(edge_emb[r] . u[l] + c[l])
__global__ void wrel_kernel(const float* __restrict__ eemb, const float* __restrict__ uc,
                            float* __restrict__ wrel) {
  int idx = blockIdx.x * blockDim.x + threadIdx.x;
  if (idx >= kL * kNE) return;
  int l = idx / kNE, r = idx % kNE;
  float z = uc[256 + l];
  const float* u = uc + l * 128;
  const float* er = eemb + (size_t)r * kD;
  for (int d = 0; d < kD; d++) z += er[d] * u[d];
  wrel[idx] = 1.f / (1.f + expf(-z));
}

// beta[l][b*V+v] = tanh(vn[b,v,:].beta_w[l] + beta_b[l]) * exp(0.01*(V-v))
__global__ void beta_kernel(const int* __restrict__ vn, const float* __restrict__ bw,
                            const float* __restrict__ bb, float* __restrict__ beta) {
  int blk = blockIdx.x;
  int l = blk / kM, r = blk % kM;
  int v = r % kV;
  int lane = threadIdx.x;
  const int* row = vn + (size_t)r * kNV;
  const float* w = bw + (size_t)l * kNV;
  float s = 0.f;
  for (int k = lane; k < kNV; k += 64) s += (float)row[k] * w[k];
  for (int off = 32; off > 0; off >>= 1) s += __shfl_down(s, off, 64);
  if (lane == 0) {
    float lam = expf(0.01f * (float)(kV - v));
    beta[blk] = tanhf(s + bb[l]) * lam;
  }
}

// VNT[b][k][v] = (float)vn[b][v][k], k padded to 1504, v padded to 32 (zeros).
// Tiled LDS transpose: block = (b, ktile of 32). Coalesced read & write.
__global__ void vnt_kernel(const int* __restrict__ vn, float* __restrict__ vnt) {
  int b = blockIdx.x, kt = blockIdx.y;
  int k0 = kt * 32;
  int tid = threadIdx.x;  // 256
  __shared__ float t[32][33];  // t[v][kk]
#pragma unroll
  for (int i = 0; i < 4; ++i) {
    int e = tid + i * 256;  // 1024 = 32v x 32k
    int v = e >> 5, kk = e & 31;
    int gk = k0 + kk;
    t[v][kk] = (v < kV && gk < kNV) ? (float)vn[(size_t)(b * kV + v) * kNV + gk] : 0.f;
  }
  __syncthreads();
  float* out = vnt + (size_t)b * kKP * 32 + (size_t)k0 * 32;
#pragma unroll
  for (int i = 0; i < 4; ++i) {
    int e = tid + i * 256;
    int kk = e >> 5, v = e & 31;
    out[kk * 32 + v] = t[v][kk];
  }
}

// Fused visit-attention, XOR-swizzled LDS (conflict-free transpose staging):
//   z[v][n] = sum_k vn[b,v,k] * aw[l][n][k]; attn = sum_v softmax_v(z)*beta.
// Block = (ntile of 128, b, l), 256 threads, thread = (n-granule, v-quad).
__global__ void fused_attn_kernel(const float* __restrict__ vnt, const float* __restrict__ aw,
                                  const float* __restrict__ beta, float* __restrict__ attn) {
  const int l = blockIdx.z, b = blockIdx.y;
  const int nb = blockIdx.x * 128;
  const int tid = threadIdx.x;  // 256
  __shared__ float smem[32 * 128 + 32 * 32];  // Bs(16KB) + VsT(4KB); Z reuses after K-loop
  float* Bs = smem;                           // k-major, granule-swizzled
  float* VsT = smem + 4096;                   // [32 k][32 v]
  const float* awl = aw + (size_t)l * kNV * kNV;
  const float* vntb = vnt + (size_t)b * kKP * 32;
  const int gIdx = tid & 31;        // n-granule (4 cols) owned in compute
  const int vg4 = (tid >> 5) * 4;   // v-quad base
  const int snn = tid >> 3;         // staging: n within 32-row group
  const int sk4 = (tid & 7) * 4;    // staging: k quad
  float acc[4][4] = {};
  for (int kt = 0; kt < kKT; ++kt) {
    const int k0 = kt * 32;
    __syncthreads();
    // ---- stage aw tile (128n x 32k) k-major with XOR granule swizzle ----
    if (k0 + 32 <= kNV) {
#pragma unroll
      for (int i = 0; i < 4; ++i) {
        int nn = snn + 32 * i;
        int gn = nb + nn;
        float4 a = (gn < kNV) ? *(const float4*)(awl + (size_t)gn * kNV + k0 + sk4)
                              : float4{0.f, 0.f, 0.f, 0.f};
        float av[4] = {a.x, a.y, a.z, a.w};
#pragma unroll
        for (int j = 0; j < 4; ++j) {
          int kk = sk4 + j;
          int g = (nn >> 2) ^ (kk >> 2);
          Bs[kk * 128 + (g << 2) + (nn & 3)] = av[j];
        }
      }
    } else {  // last chunk: per-element guards
#pragma unroll
      for (int i = 0; i < 4; ++i) {
        int nn = snn + 32 * i;
        int gn = nb + nn;
#pragma unroll
        for (int j = 0; j < 4; ++j) {
          int kk = sk4 + j;
          int gk = k0 + kk;
          float v = (gn < kNV && gk < kNV) ? awl[(size_t)gn * kNV + gk] : 0.f;
          int g = (nn >> 2) ^ (kk >> 2);
          Bs[kk * 128 + (g << 2) + (nn & 3)] = v;
        }
      }
    }
    {  // ---- stage VNT chunk (32k x 32v), direct float4 ----
      int kk = tid >> 3, v4 = (tid & 7) * 4;
      *(float4*)&VsT[kk * 32 + v4] = *(const float4*)(vntb + (size_t)(k0 + kk) * 32 + v4);
    }
    __syncthreads();
    // ---- compute: 32 k-steps, 4v x 4n per thread ----
#pragma unroll 8
    for (int kk = 0; kk < 32; ++kk) {
      float4 bv = *(const float4*)&Bs[kk * 128 + ((gIdx ^ (kk >> 2)) << 2)];
      float4 vv = *(const float4*)&VsT[kk * 32 + vg4];
      acc[0][0] += vv.x * bv.x; acc[0][1] += vv.x * bv.y; acc[0][2] += vv.x * bv.z; acc[0][3] += vv.x * bv.w;
      acc[1][0] += vv.y * bv.x; acc[1][1] += vv.y * bv.y; acc[1][2] += vv.y * bv.z; acc[1][3] += vv.y * bv.w;
      acc[2][0] += vv.z * bv.x; acc[2][1] += vv.z * bv.y; acc[2][2] += vv.z * bv.z; acc[2][3] += vv.z * bv.w;
      acc[3][0] += vv.w * bv.x; acc[3][1] += vv.w * bv.y; acc[3][2] += vv.w * bv.z; acc[3][3] += vv.w * bv.w;
    }
  }
  __syncthreads();
  // ---- epilogue: Z[v][n'] in reused smem, then softmax*beta ----
  float* Z = smem;  // [kV][128]
  const int nc4 = gIdx * 4;
#pragma unroll
  for (int i = 0; i < 4; ++i) {
    int v = vg4 + i;
    if (v < kV) *(float4*)&Z[v * 128 + nc4] = float4{acc[i][0], acc[i][1], acc[i][2], acc[i][3]};
  }
  __syncthreads();
  if (tid < 128) {
    int n = nb + tid;
    if (n < kNV) {
      float zz[kV];
      float m = -1e30f;
#pragma unroll
      for (int v = 0; v < kV; ++v) {
        zz[v] = Z[v * 128 + tid];
        m = fmaxf(m, zz[v]);
      }
      const float* bet = beta + (size_t)l * kM + b * kV;
      float s = 0.f, num = 0.f;
#pragma unroll
      for (int v = 0; v < kV; ++v) {
        float e = expf(zz[v] - m);
        s += e;
        num += e * bet[v];
      }
      attn[(size_t)(l * kB + b) * kNV + n] = num / s;
    }
  }
}

// ---- CSR build ----
__global__ void hist_kernel(const int* __restrict__ dst, int* __restrict__ deg) {
  int e = blockIdx.x * blockDim.x + threadIdx.x;
  if (e >= kE) return;
  atomicAdd(&deg[dst[e]], 1);
}

__global__ void scan1_kernel(const int* __restrict__ deg, int* __restrict__ off,
                             int* __restrict__ part) {
  int t = threadIdx.x, i = blockIdx.x * 256 + t;
  int v = (i < kNT) ? deg[i] : 0;
  __shared__ int sm[256];
  sm[t] = v;
  __syncthreads();
  for (int o = 1; o < 256; o <<= 1) {
    int x = (t >= o) ? sm[t - o] : 0;
    __syncthreads();
    sm[t] += x;
    __syncthreads();
  }
  if (i < kNT) off[i] = sm[t] - v;
  if (t == 255) part[blockIdx.x] = sm[255];
}

__global__ void scan2_kernel(int* __restrict__ part) {
  int t = threadIdx.x;  // 512
  int v = (t < kNB) ? part[t] : 0;
  __shared__ int sm[512];
  sm[t] = v;
  __syncthreads();
  for (int o = 1; o < 512; o <<= 1) {
    int x = (t >= o) ? sm[t - o] : 0;
    __syncthreads();
    sm[t] += x;
    __syncthreads();
  }
  if (t < kNB) part[t] = sm[t] - v;
}

__global__ void scan3_kernel(int* __restrict__ off, const int* __restrict__ part,
                             int* __restrict__ cursor) {
  int i = blockIdx.x * 256 + threadIdx.x;
  if (i >= kNT) return;
  int o = off[i] + part[blockIdx.x];
  off[i] = o;
  cursor[i] = o;
}

// scatter edges into CSR slots; precompute per-edge scalars for both layers
__global__ void scatter_kernel(const int* __restrict__ ei, const int* __restrict__ nid,
                               const int* __restrict__ eid, const int* __restrict__ batch,
                               const float* __restrict__ attn, const float* __restrict__ wrel,
                               int* __restrict__ cursor, int* __restrict__ csrc,
                               float* __restrict__ cs0, float* __restrict__ cs1) {
  int e = blockIdx.x * blockDim.x + threadIdx.x;
  if (e >= kE) return;
  int s = ei[e], d = ei[kE + e];
  int b = batch[s], n = nid[s], r = eid[e];
  float a0 = attn[(size_t)b * kNV + n];
  float a1 = attn[(size_t)kB * kNV + b * kNV + n];
  float w0 = wrel[r], w1 = wrel[kNE + r];
  int pos = atomicAdd(&cursor[d], 1);
  csrc[pos] = s;
  cs0[pos] = a0 * w0;
  cs1[pos] = a1 * w1;
}

// rows[n] = x[n] + sum_{edges->n} relu(x[src]*scal)
__global__ void gather_kernel(const float* __restrict__ x, const int* __restrict__ csrc,
                              const float* __restrict__ cscal, const int* __restrict__ off,
                              const int* __restrict__ endv, float* __restrict__ rows) {
  int wid = (blockIdx.x * blockDim.x + threadIdx.x) >> 6;
  int lane = threadIdx.x & 63;
  int sub = lane >> 5, sl = lane & 31;
  int node = wid * 2 + sub;
  if (node >= kNT) return;
  const float4* x4 = (const float4*)x;
  float4 acc = x4[(size_t)node * 32 + sl];
  int j0 = off[node], j1 = endv[node];
  for (int base = j0; base < j1; base += 32) {
    int n = j1 - base;
    if (n > 32) n = 32;
    int sidx = 0;
    float ssc = 0.f;
    if (sl < n) {
      sidx = csrc[base + sl];
      ssc = cscal[base + sl];
    }
    for (int t = 0; t < n; ++t) {
      int s = __shfl(sidx, sub * 32 + t, 64);
      float sc = __shfl(ssc, sub * 32 + t, 64);
      float4 xv = x4[(size_t)s * 32 + sl];
      acc.x += fmaxf(xv.x * sc, 0.f);
      acc.y += fmaxf(xv.y * sc, 0.f);
      acc.z += fmaxf(xv.z * sc, 0.f);
      acc.w += fmaxf(xv.w * sc, 0.f);
    }
  }
  ((float4*)rows)[(size_t)node * 32 + sl] = acc;
}

// x_out[n][h] = relu(rows[n] . w[h] + bias[h]); 128 nodes/block, 8x8/thread
__global__ void conv_kernel(const float* __restrict__ rows, const float* __restrict__ w,
                            const float* __restrict__ bias, float* __restrict__ xout) {
  const int nb = blockIdx.x * 128;
  const int tid = threadIdx.x;  // 256
  __shared__ float As[32][132];
  __shared__ float Bs[32][132];
  const int tx = tid & 15, ty = tid >> 4;
  const int m0 = ty * 8;
  const int n0 = tx * 4;
  float acc[8][8] = {};
  for (int kc = 0; kc < 4; ++kc) {
    __syncthreads();
#pragma unroll
    for (int i = 0; i < 4; ++i) {
      int fi = tid + i * 256;
      int rr = fi >> 3, c4 = (fi & 7) * 4;
      int gr = nb + rr;
      float4 v = (gr < kNT) ? *(const float4*)(rows + (size_t)gr * kD + kc * 32 + c4)
                            : float4{0.f, 0.f, 0.f, 0.f};
      As[c4 + 0][rr] = v.x;
      As[c4 + 1][rr] = v.y;
      As[c4 + 2][rr] = v.z;
      As[c4 + 3][rr] = v.w;
    }
#pragma unroll
    for (int i = 0; i < 4; ++i) {
      int fi = tid + i * 256;
      int hh = fi >> 3, c4 = (fi & 7) * 4;
      float4 v = *(const float4*)(w + (size_t)hh * kD + kc * 32 + c4);
      Bs[c4 + 0][hh] = v.x;
      Bs[c4 + 1][hh] = v.y;
      Bs[c4 + 2][hh] = v.z;
      Bs[c4 + 3][hh] = v.w;
    }
    __syncthreads();
#pragma unroll
    for (int d = 0; d < 32; ++d) {
      float4 a0 = *(const float4*)&As[d][m0];
      float4 a1 = *(const float4*)&As[d][m0 + 4];
      float4 b0 = *(const float4*)&Bs[d][n0];
      float4 b1 = *(const float4*)&Bs[d][n0 + 64];
      float am[8] = {a0.x, a0.y, a0.z, a0.w, a1.x, a1.y, a1.z, a1.w};
      float bn[8] = {b0.x, b0.y, b0.z, b0.w, b1.x, b1.y, b1.z, b1.w};
#pragma unroll
      for (int i2 = 0; i2 < 8; ++i2)
#pragma unroll
        for (int j2 = 0; j2 < 8; ++j2) acc[i2][j2] += am[i2] * bn[j2];
    }
  }
  float4 bv0 = *(const float4*)(bias + n0);
  float4 bv1 = *(const float4*)(bias + 64 + n0);
#pragma unroll
  for (int i2 = 0; i2 < 8; ++i2) {
    int r = nb + m0 + i2;
    if (r >= kNT) break;
    float4 o0, o1;
    o0.x = fmaxf(acc[i2][0] + bv0.x, 0.f);
    o0.y = fmaxf(acc[i2][1] + bv0.y, 0.f);
    o0.z = fmaxf(acc[i2][2] + bv0.z, 0.f);
    o0.w = fmaxf(acc[i2][3] + bv0.w, 0.f);
    o1.x = fmaxf(acc[i2][4] + bv1.x, 0.f);
    o1.y = fmaxf(acc[i2][5] + bv1.y, 0.f);
    o1.z = fmaxf(acc[i2][6] + bv1.z, 0.f);
    o1.w = fmaxf(acc[i2][7] + bv1.w, 0.f);
    *(float4*)(xout + (size_t)r * kH + n0) = o0;
    *(float4*)(xout + (size_t)r * kH + 64 + n0) = o1;
  }
}

// mean-pool: register accumulation with flush-on-batch-change
__global__ void pool_kernel(const float* __restrict__ x, const int* __restrict__ batch,
                            float* __restrict__ xg, int* __restrict__ cnt) {
  int h = threadIdx.x;  // 128
  int start = blockIdx.x * 256;
  int end = start + 256;
  if (end > kNT) end = kNT;
  int cur = batch[start];
  float acc = 0.f;
  int c = 0;
  for (int i = start; i < end; i++) {
    int bb = batch[i];
    if (bb != cur) {
      atomicAdd(&xg[cur * kH + h], acc);
      if (h == 0) atomicAdd(&cnt[cur], c);
      acc = 0.f;
      c = 0;
      cur = bb;
    }
    acc += x[(size_t)i * kH + h];
    c++;
  }
  atomicAdd(&xg[cur * kH + h], acc);
  if (h == 0) atomicAdd(&cnt[cur], c);
}

// out[b][o] = concat(xg[b]/cnt[b], xacc[b]/cnte[b]) . mlp_w[o] + mlp_b[o]
__global__ void final_kernel(const float* __restrict__ xg, const int* __restrict__ cnt,
                             const float* __restrict__ xacc, const int* __restrict__ cnte,
                             const float* __restrict__ mw, const float* __restrict__ mb,
                             float* __restrict__ out) {
  int idx = blockIdx.x * blockDim.x + threadIdx.x;
  if (idx >= kB * kOut) return;
  int b = idx / kOut, o = idx % kOut;
  float invg = 1.f / (float)cnt[b];
  float invn = 1.f / (float)cnte[b];
  float acc = mb[o];
  const float* w = mw + (size_t)o * (2 * kH);
  for (int h = 0; h < kH; h++) acc += xg[b * kH + h] * invg * w[h];
  for (int h = 0; h < kH; h++) acc += xacc[b * kH + h] * invn * w[kH + h];
  out[idx] = acc;
}

extern "C" void kernel_launch(void* const* d_in, const int* in_sizes, int n_in,
                              void* d_out, int out_size, void* d_ws, size_t ws_size,
                              hipStream_t stream) {
  const float* node_emb = (const float*)d_in[0];
  const float* edge_emb = (const float*)d_in[1];
  const float* lin_w = (const float*)d_in[2];
  const float* lin_b = (const float*)d_in[3];
  const float* alpha_w = (const float*)d_in[4];
  const float* alpha_b = (const float*)d_in[5];
  const float* beta_w = (const float*)d_in[6];
  const float* beta_b = (const float*)d_in[7];
  const float* wr_w = (const float*)d_in[8];
  const float* wr_b = (const float*)d_in[9];
  const float* conv_w = (const float*)d_in[10];
  const float* conv_b = (const float*)d_in[11];
  const float* mlp_w = (const float*)d_in[12];
  const float* mlp_b = (const float*)d_in[13];
  const int* visit_node = (const int*)d_in[14];
  const int* ehr_nodes = (const int*)d_in[15];
  const int* cat_node_ids = (const int*)d_in[16];
  const int* cat_edge_ids = (const int*)d_in[17];
  const int* edge_index = (const int*)d_in[18];
  const int* batch = (const int*)d_in[19];

  char* ws = (char*)d_ws;
  float* X = (float*)(ws);                            // 51,200,000
  float* ROWS = (float*)(ws + 51200000);              // 51,200,000
  float* PN = ROWS;                                   // alias (dead before ROWS used)
  float* VNT = (float*)(ws + 51200000 + 1048576);     // 3,080,192 (alias in ROWS; dead too)
  float* ATTN = (float*)(ws + 102400000);             // 192,128
  float* BETA = (float*)(ws + 102592256);             // 3,840
  float* UC = (float*)(ws + 102596352);               // 1,032
  float* WREL = (float*)(ws + 102597632);             // 16,008
  int* OFF = (int*)(ws + 102613760);                  // 400,004
  int* CURSOR = (int*)(ws + 103014016);               // 400,000 (also DEG)
  int* SPART = (int*)(ws + 103414016);                // 2,048
  int* CSRS = (int*)(ws + 103416064);                 // 3,200,000
  float* CS0 = (float*)(ws + 106616064);              // 3,200,000
  float* CS1 = (float*)(ws + 109816064);              // 3,200,000
  float* XG = (float*)(ws + 113016064);               // 8,192
  int* CNT = (int*)(ws + 113024256);                  // 64
  float* XNACC = (float*)(ws + 113024320);            // 8,192
  int* CNTE = (int*)(ws + 113032512);                 // 64

  pn_kernel<<<kNV, kH, 0, stream>>>(node_emb, lin_w, lin_b, PN);
  xinit_kernel<<<(kNT * 32 + 255) / 256, 256, 0, stream>>>((const float4*)PN, cat_node_ids,
                                                           (float4*)X);
  hipMemsetAsync(XG, 0, 16512, stream);
  xnode_kernel<<<dim3(kB, 12), kH, 0, stream>>>(ehr_nodes, PN, XNACC, CNTE);
  uc_kernel<<<1, 256, 0, stream>>>(wr_w, wr_b, lin_w, lin_b, UC);
  wrel_kernel<<<(kL * kNE + 255) / 256, 256, 0, stream>>>(edge_emb, UC, WREL);
  beta_kernel<<<kL * kM, 64, 0, stream>>>(visit_node, beta_w, beta_b, BETA);
  vnt_kernel<<<dim3(kB, kKT), 256, 0, stream>>>(visit_node, VNT);
  fused_attn_kernel<<<dim3((kNV + 127) / 128, kB, kL), 256, 0, stream>>>(VNT, alpha_w, BETA,
                                                                         ATTN);

  const int* dst = edge_index + kE;
  hipMemsetAsync(CURSOR, 0, kNT * 4, stream);
  hist_kernel<<<(kE + 255) / 256, 256, 0, stream>>>(dst, CURSOR);
  scan1_kernel<<<kNB, 256, 0, stream>>>(CURSOR, OFF, SPART);
  scan2_kernel<<<1, 512, 0, stream>>>(SPART);
  scan3_kernel<<<kNB, 256, 0, stream>>>(OFF, SPART, CURSOR);
  scatter_kernel<<<(kE + 255) / 256, 256, 0, stream>>>(edge_index, cat_node_ids, cat_edge_ids,
                                                       batch, ATTN, WREL, CURSOR, CSRS, CS0, CS1);

  for (int l = 0; l < kL; l++) {
    gather_kernel<<<kNT / 8, 256, 0, stream>>>(X, CSRS, (l ? CS1 : CS0), OFF, CURSOR, ROWS);
    conv_kernel<<<(kNT + 127) / 128, 256, 0, stream>>>(ROWS, conv_w + (size_t)l * kH * kD,
                                                       conv_b + (size_t)l * kH, X);
  }

  pool_kernel<<<(kNT + 255) / 256, kH, 0, stream>>>(X, batch, XG, CNT);
  final_kernel<<<2, 256, 0, stream>>>(XG, CNT, XNACC, CNTE, mlp_w, mlp_b, (float*)d_out);
}

// Round 8
// 646.460 us; speedup vs baseline: 1.5165x; 1.0956x over previous
//
#include <hip/hip_runtime.h>
#include <math.h>

namespace {
constexpr int kB = 16, kV = 30, kNV = 1501, kNE = 2001, kH = 128, kD = 128,
              kL = 2, kOut = 25, kNT = 100000, kE = 800000, kM = kB * kV;
constexpr int kNB = (kNT + 255) / 256;  // 391 scan blocks
constexpr int kKT = 47;                 // k-chunks of 32 (47*32 = 1504 >= 1501)
constexpr int kKP = kKT * 32;           // padded K = 1504
constexpr int kKSZ = 4;                 // split-K blocks for z
constexpr int kNVZ = 1536;              // padded n-stride for z partials
}

// Pn[n][h] = node_emb[n] . lin_w[h] + lin_b[h]
__global__ void pn_kernel(const float* __restrict__ emb, const float* __restrict__ lw,
                          const float* __restrict__ lb, float* __restrict__ pn) {
  int n = blockIdx.x, h = threadIdx.x;
  __shared__ float row[kD];
  row[h] = emb[(size_t)n * kD + h];
  __syncthreads();
  float acc = lb[h];
#pragma unroll 8
  for (int d = 0; d < kD; d++) acc += row[d] * lw[h * kD + d];
  pn[(size_t)n * kH + h] = acc;
}

// x[i] = Pn[cat_node_ids[i]]
__global__ void xinit_kernel(const float4* __restrict__ pn4, const int* __restrict__ nid,
                             float4* __restrict__ x4) {
  int t = blockIdx.x * blockDim.x + threadIdx.x;
  if (t >= kNT * 32) return;
  int i = t >> 5, c = t & 31;
  x4[(size_t)i * 32 + c] = pn4[(size_t)nid[i] * 32 + c];
}

// node branch partials
__global__ void xnode_kernel(const int* __restrict__ ehr, const float* __restrict__ pn,
                             float* __restrict__ xacc, int* __restrict__ cnte) {
  int b = blockIdx.x;
  int c = blockIdx.y;
  int h = threadIdx.x;
  int n0 = c * 128;
  __shared__ int flags[128];
  int gn = n0 + h;
  flags[h] = (gn < kNV) ? ehr[(size_t)b * kNV + gn] : 0;
  __syncthreads();
  float acc = 0.f;
  int cnt = 0;
  int n1 = min(n0 + 128, kNV);
  for (int n = n0; n < n1; ++n) {
    if (flags[n - n0]) {
      acc += pn[(size_t)n * kH + h];
      cnt++;
    }
  }
  atomicAdd(&xacc[b * kH + h], acc);
  if (h == 0) atomicAdd(&cnte[b], cnt);
}

// u[l][d] = sum_h wr_w[l][h]*lin_w[h][d] ; c[l] = wr_w[l].lin_b + wr_b[l]
__global__ void uc_kernel(const float* __restrict__ wrw, const float* __restrict__ wrb,
                          const float* __restrict__ lw, const float* __restrict__ lb,
                          float* __restrict__ uc) {
  int t = threadIdx.x;
  int l = t >> 7, d = t & 127;
  float s = 0.f;
  for (int h = 0; h < kH; h++) s += wrw[l * kH + h] * lw[h * kD + d];
  uc[t] = s;
  if (t < kL) {
    float c = wrb[t];
    for (int h = 0; h < kH; h++) c += wrw[t * kH + h] * lb[h];
    uc[256 + t] = c;
  }
}

// wrel[l][r] = sigmoid(edge_emb[r] . u[l] + c[l])
__global__ void wrel_kernel(const float* __restrict__ eemb, const float* __restrict__ uc,
                            float* __restrict__ wrel) {
  int idx = blockIdx.x * blockDim.x + threadIdx.x;
  if (idx >= kL * kNE) return;
  int l = idx / kNE, r = idx % kNE;
  float z = uc[256 + l];
  const float* u = uc + l * 128;
  const float* er = eemb + (size_t)r * kD;
  for (int d = 0; d < kD; d++) z += er[d] * u[d];
  wrel[idx] = 1.f / (1.f + expf(-z));
}

// beta[l][b*V+v] = tanh(vn[b,v,:].beta_w[l] + beta_b[l]) * exp(0.01*(V-v))
__global__ void beta_kernel(const int* __restrict__ vn, const float* __restrict__ bw,
                            const float* __restrict__ bb, float* __restrict__ beta) {
  int blk = blockIdx.x;
  int l = blk / kM, r = blk % kM;
  int v = r % kV;
  int lane = threadIdx.x;
  const int* row = vn + (size_t)r * kNV;
  const float* w = bw + (size_t)l * kNV;
  float s = 0.f;
  for (int k = lane; k < kNV; k += 64) s += (float)row[k] * w[k];
  for (int off = 32; off > 0; off >>= 1) s += __shfl_down(s, off, 64);
  if (lane == 0) {
    float lam = expf(0.01f * (float)(kV - v));
    beta[blk] = tanhf(s + bb[l]) * lam;
  }
}

// VNT[b][k][v] = (float)vn[b][v][k], k padded to 1504, v padded to 32 (zeros).
__global__ void vnt_kernel(const int* __restrict__ vn, float* __restrict__ vnt) {
  int b = blockIdx.x, kt = blockIdx.y;
  int k0 = kt * 32;
  int tid = threadIdx.x;  // 256
  __shared__ float t[32][33];  // t[v][kk]
#pragma unroll
  for (int i = 0; i < 4; ++i) {
    int e = tid + i * 256;  // 1024 = 32v x 32k
    int v = e >> 5, kk = e & 31;
    int gk = k0 + kk;
    t[v][kk] = (v < kV && gk < kNV) ? (float)vn[(size_t)(b * kV + v) * kNV + gk] : 0.f;
  }
  __syncthreads();
  float* out = vnt + (size_t)b * kKP * 32 + (size_t)k0 * 32;
#pragma unroll
  for (int i = 0; i < 4; ++i) {
    int e = tid + i * 256;
    int kk = e >> 5, v = e & 31;
    out[kk * 32 + v] = t[v][kk];
  }
}

// Split-K partial z: zp[ks][l][b][v][n] = sum_{k in slice ks} vn[b,v,k]*aw[l][n][k]
// Block = (ntile of 128, b, l*kKSZ+ks), 256 threads, XOR-swizzled LDS staging.
__global__ void zpart_kernel(const float* __restrict__ vnt, const float* __restrict__ aw,
                             float* __restrict__ zp) {
  const int zidx = blockIdx.z;
  const int l = zidx / kKSZ, ks = zidx % kKSZ;
  const int b = blockIdx.y;
  const int nb = blockIdx.x * 128;
  const int tid = threadIdx.x;  // 256
  __shared__ float smem[32 * 128 + 32 * 32];  // Bs(16KB) + VsT(4KB)
  float* Bs = smem;
  float* VsT = smem + 4096;
  const float* awl = aw + (size_t)l * kNV * kNV;
  const float* vntb = vnt + (size_t)b * kKP * 32;
  const int gIdx = tid & 31;       // n-granule in compute
  const int vg4 = (tid >> 5) * 4;  // v-quad base
  const int snn = tid >> 3;        // staging n within 32-row group
  const int sk4 = (tid & 7) * 4;   // staging k quad
  const int ct0 = ks * 12;
  const int ct1 = min(ct0 + 12, kKT);
  float acc[4][4] = {};
  for (int kt = ct0; kt < ct1; ++kt) {
    const int k0 = kt * 32;
    __syncthreads();
    // ---- stage aw tile (128n x 32k) k-major with XOR granule swizzle ----
    if (k0 + 32 <= kNV) {
#pragma unroll
      for (int i = 0; i < 4; ++i) {
        int nn = snn + 32 * i;
        int gn = nb + nn;
        float4 a = (gn < kNV) ? *(const float4*)(awl + (size_t)gn * kNV + k0 + sk4)
                              : float4{0.f, 0.f, 0.f, 0.f};
        float av[4] = {a.x, a.y, a.z, a.w};
#pragma unroll
        for (int j = 0; j < 4; ++j) {
          int kk = sk4 + j;
          int g = (nn >> 2) ^ (kk >> 2);
          Bs[kk * 128 + (g << 2) + (nn & 3)] = av[j];
        }
      }
    } else {  // last chunk: per-element guards
#pragma unroll
      for (int i = 0; i < 4; ++i) {
        int nn = snn + 32 * i;
        int gn = nb + nn;
#pragma unroll
        for (int j = 0; j < 4; ++j) {
          int kk = sk4 + j;
          int gk = k0 + kk;
          float v = (gn < kNV && gk < kNV) ? awl[(size_t)gn * kNV + gk] : 0.f;
          int g = (nn >> 2) ^ (kk >> 2);
          Bs[kk * 128 + (g << 2) + (nn & 3)] = v;
        }
      }
    }
    {  // ---- stage VNT chunk (32k x 32v), direct float4 ----
      int kk = tid >> 3, v4 = (tid & 7) * 4;
      *(float4*)&VsT[kk * 32 + v4] = *(const float4*)(vntb + (size_t)(k0 + kk) * 32 + v4);
    }
    __syncthreads();
#pragma unroll 8
    for (int kk = 0; kk < 32; ++kk) {
      float4 bv = *(const float4*)&Bs[kk * 128 + ((gIdx ^ (kk >> 2)) << 2)];
      float4 vv = *(const float4*)&VsT[kk * 32 + vg4];
      acc[0][0] += vv.x * bv.x; acc[0][1] += vv.x * bv.y; acc[0][2] += vv.x * bv.z; acc[0][3] += vv.x * bv.w;
      acc[1][0] += vv.y * bv.x; acc[1][1] += vv.y * bv.y; acc[1][2] += vv.y * bv.z; acc[1][3] += vv.y * bv.w;
      acc[2][0] += vv.z * bv.x; acc[2][1] += vv.z * bv.y; acc[2][2] += vv.z * bv.z; acc[2][3] += vv.z * bv.w;
      acc[3][0] += vv.w * bv.x; acc[3][1] += vv.w * bv.y; acc[3][2] += vv.w * bv.z; acc[3][3] += vv.w * bv.w;
    }
  }
  // ---- write partials (float4, unguarded n thanks to kNVZ=1536 pad) ----
  float* zb = zp + (size_t)(ks * kL * kB + l * kB + b) * 32 * kNVZ;
  const int nc4 = gIdx * 4;
#pragma unroll
  for (int i = 0; i < 4; ++i) {
    int v = vg4 + i;
    if (v < kV)
      *(float4*)&zb[(size_t)v * kNVZ + nb + nc4] =
          float4{acc[i][0], acc[i][1], acc[i][2], acc[i][3]};
  }
}

// attn[l][b][n] = sum_v softmax_v(sum_ks zp) * beta[l][b][v]
__global__ void zsm_kernel(const float* __restrict__ zp, const float* __restrict__ beta,
                           float* __restrict__ attn) {
  int idx = blockIdx.x * blockDim.x + threadIdx.x;
  if (idx >= kL * kB * kNV) return;
  int n = idx % kNV;
  int lb_ = idx / kNV;  // l*kB + b
  const size_t PS = (size_t)kL * kB * 32 * kNVZ;  // partial stride
  const float* p = zp + (size_t)lb_ * 32 * kNVZ + n;
  float zz[kV];
  float m = -1e30f;
#pragma unroll
  for (int v = 0; v < kV; ++v) {
    size_t o = (size_t)v * kNVZ;
    float s = p[o] + p[o + PS] + p[o + 2 * PS] + p[o + 3 * PS];
    zz[v] = s;
    m = fmaxf(m, s);
  }
  float s = 0.f, num = 0.f;
  const float* bet = beta + lb_ * kV;
#pragma unroll
  for (int v = 0; v < kV; ++v) {
    float e = expf(zz[v] - m);
    s += e;
    num += e * bet[v];
  }
  attn[idx] = num / s;
}

// ---- CSR build ----
__global__ void hist_kernel(const int* __restrict__ dst, int* __restrict__ deg) {
  int e = blockIdx.x * blockDim.x + threadIdx.x;
  if (e >= kE) return;
  atomicAdd(&deg[dst[e]], 1);
}

__global__ void scan1_kernel(const int* __restrict__ deg, int* __restrict__ off,
                             int* __restrict__ part) {
  int t = threadIdx.x, i = blockIdx.x * 256 + t;
  int v = (i < kNT) ? deg[i] : 0;
  __shared__ int sm[256];
  sm[t] = v;
  __syncthreads();
  for (int o = 1; o < 256; o <<= 1) {
    int x = (t >= o) ? sm[t - o] : 0;
    __syncthreads();
    sm[t] += x;
    __syncthreads();
  }
  if (i < kNT) off[i] = sm[t] - v;
  if (t == 255) part[blockIdx.x] = sm[255];
}

__global__ void scan2_kernel(int* __restrict__ part) {
  int t = threadIdx.x;  // 512
  int v = (t < kNB) ? part[t] : 0;
  __shared__ int sm[512];
  sm[t] = v;
  __syncthreads();
  for (int o = 1; o < 512; o <<= 1) {
    int x = (t >= o) ? sm[t - o] : 0;
    __syncthreads();
    sm[t] += x;
    __syncthreads();
  }
  if (t < kNB) part[t] = sm[t] - v;
}

__global__ void scan3_kernel(int* __restrict__ off, const int* __restrict__ part,
                             int* __restrict__ cursor) {
  int i = blockIdx.x * 256 + threadIdx.x;
  if (i >= kNT) return;
  int o = off[i] + part[blockIdx.x];
  off[i] = o;
  cursor[i] = o;
}

// scatter edges into CSR slots; precompute per-edge scalars for both layers
__global__ void scatter_kernel(const int* __restrict__ ei, const int* __restrict__ nid,
                               const int* __restrict__ eid, const int* __restrict__ batch,
                               const float* __restrict__ attn, const float* __restrict__ wrel,
                               int* __restrict__ cursor, int* __restrict__ csrc,
                               float* __restrict__ cs0, float* __restrict__ cs1) {
  int e = blockIdx.x * blockDim.x + threadIdx.x;
  if (e >= kE) return;
  int s = ei[e], d = ei[kE + e];
  int b = batch[s], n = nid[s], r = eid[e];
  float a0 = attn[(size_t)b * kNV + n];
  float a1 = attn[(size_t)kB * kNV + b * kNV + n];
  float w0 = wrel[r], w1 = wrel[kNE + r];
  int pos = atomicAdd(&cursor[d], 1);
  csrc[pos] = s;
  cs0[pos] = a0 * w0;
  cs1[pos] = a1 * w1;
}

// rows[n] = x[n] + sum_{edges->n} relu(x[src]*scal)
__global__ void gather_kernel(const float* __restrict__ x, const int* __restrict__ csrc,
                              const float* __restrict__ cscal, const int* __restrict__ off,
                              const int* __restrict__ endv, float* __restrict__ rows) {
  int wid = (blockIdx.x * blockDim.x + threadIdx.x) >> 6;
  int lane = threadIdx.x & 63;
  int sub = lane >> 5, sl = lane & 31;
  int node = wid * 2 + sub;
  if (node >= kNT) return;
  const float4* x4 = (const float4*)x;
  float4 acc = x4[(size_t)node * 32 + sl];
  int j0 = off[node], j1 = endv[node];
  for (int base = j0; base < j1; base += 32) {
    int n = j1 - base;
    if (n > 32) n = 32;
    int sidx = 0;
    float ssc = 0.f;
    if (sl < n) {
      sidx = csrc[base + sl];
      ssc = cscal[base + sl];
    }
    for (int t = 0; t < n; ++t) {
      int s = __shfl(sidx, sub * 32 + t, 64);
      float sc = __shfl(ssc, sub * 32 + t, 64);
      float4 xv = x4[(size_t)s * 32 + sl];
      acc.x += fmaxf(xv.x * sc, 0.f);
      acc.y += fmaxf(xv.y * sc, 0.f);
      acc.z += fmaxf(xv.z * sc, 0.f);
      acc.w += fmaxf(xv.w * sc, 0.f);
    }
  }
  ((float4*)rows)[(size_t)node * 32 + sl] = acc;
}

// x_out[n][h] = relu(rows[n] . w[h] + bias[h]); 128 nodes/block, 8x8/thread
__global__ void conv_kernel(const float* __restrict__ rows, const float* __restrict__ w,
                            const float* __restrict__ bias, float* __restrict__ xout) {
  const int nb = blockIdx.x * 128;
  const int tid = threadIdx.x;  // 256
  __shared__ float As[32][132];
  __shared__ float Bs[32][132];
  const int tx = tid & 15, ty = tid >> 4;
  const int m0 = ty * 8;
  const int n0 = tx * 4;
  float acc[8][8] = {};
  for (int kc = 0; kc < 4; ++kc) {
    __syncthreads();
#pragma unroll
    for (int i = 0; i < 4; ++i) {
      int fi = tid + i * 256;
      int rr = fi >> 3, c4 = (fi & 7) * 4;
      int gr = nb + rr;
      float4 v = (gr < kNT) ? *(const float4*)(rows + (size_t)gr * kD + kc * 32 + c4)
                            : float4{0.f, 0.f, 0.f, 0.f};
      As[c4 + 0][rr] = v.x;
      As[c4 + 1][rr] = v.y;
      As[c4 + 2][rr] = v.z;
      As[c4 + 3][rr] = v.w;
    }
#pragma unroll
    for (int i = 0; i < 4; ++i) {
      int fi = tid + i * 256;
      int hh = fi >> 3, c4 = (fi & 7) * 4;
      float4 v = *(const float4*)(w + (size_t)hh * kD + kc * 32 + c4);
      Bs[c4 + 0][hh] = v.x;
      Bs[c4 + 1][hh] = v.y;
      Bs[c4 + 2][hh] = v.z;
      Bs[c4 + 3][hh] = v.w;
    }
    __syncthreads();
#pragma unroll
    for (int d = 0; d < 32; ++d) {
      float4 a0 = *(const float4*)&As[d][m0];
      float4 a1 = *(const float4*)&As[d][m0 + 4];
      float4 b0 = *(const float4*)&Bs[d][n0];
      float4 b1 = *(const float4*)&Bs[d][n0 + 64];
      float am[8] = {a0.x, a0.y, a0.z, a0.w, a1.x, a1.y, a1.z, a1.w};
      float bn[8] = {b0.x, b0.y, b0.z, b0.w, b1.x, b1.y, b1.z, b1.w};
#pragma unroll
      for (int i2 = 0; i2 < 8; ++i2)
#pragma unroll
        for (int j2 = 0; j2 < 8; ++j2) acc[i2][j2] += am[i2] * bn[j2];
    }
  }
  float4 bv0 = *(const float4*)(bias + n0);
  float4 bv1 = *(const float4*)(bias + 64 + n0);
#pragma unroll
  for (int i2 = 0; i2 < 8; ++i2) {
    int r = nb + m0 + i2;
    if (r >= kNT) break;
    float4 o0, o1;
    o0.x = fmaxf(acc[i2][0] + bv0.x, 0.f);
    o0.y = fmaxf(acc[i2][1] + bv0.y, 0.f);
    o0.z = fmaxf(acc[i2][2] + bv0.z, 0.f);
    o0.w = fmaxf(acc[i2][3] + bv0.w, 0.f);
    o1.x = fmaxf(acc[i2][4] + bv1.x, 0.f);
    o1.y = fmaxf(acc[i2][5] + bv1.y, 0.f);
    o1.z = fmaxf(acc[i2][6] + bv1.z, 0.f);
    o1.w = fmaxf(acc[i2][7] + bv1.w, 0.f);
    *(float4*)(xout + (size_t)r * kH + n0) = o0;
    *(float4*)(xout + (size_t)r * kH + 64 + n0) = o1;
  }
}

// mean-pool: register accumulation with flush-on-batch-change
__global__ void pool_kernel(const float* __restrict__ x, const int* __restrict__ batch,
                            float* __restrict__ xg, int* __restrict__ cnt) {
  int h = threadIdx.x;  // 128
  int start = blockIdx.x * 256;
  int end = start + 256;
  if (end > kNT) end = kNT;
  int cur = batch[start];
  float acc = 0.f;
  int c = 0;
  for (int i = start; i < end; i++) {
    int bb = batch[i];
    if (bb != cur) {
      atomicAdd(&xg[cur * kH + h], acc);
      if (h == 0) atomicAdd(&cnt[cur], c);
      acc = 0.f;
      c = 0;
      cur = bb;
    }
    acc += x[(size_t)i * kH + h];
    c++;
  }
  atomicAdd(&xg[cur * kH + h], acc);
  if (h == 0) atomicAdd(&cnt[cur], c);
}

// out[b][o] = concat(xg[b]/cnt[b], xacc[b]/cnte[b]) . mlp_w[o] + mlp_b[o]
__global__ void final_kernel(const float* __restrict__ xg, const int* __restrict__ cnt,
                             const float* __restrict__ xacc, const int* __restrict__ cnte,
                             const float* __restrict__ mw, const float* __restrict__ mb,
                             float* __restrict__ out) {
  int idx = blockIdx.x * blockDim.x + threadIdx.x;
  if (idx >= kB * kOut) return;
  int b = idx / kOut, o = idx % kOut;
  float invg = 1.f / (float)cnt[b];
  float invn = 1.f / (float)cnte[b];
  float acc = mb[o];
  const float* w = mw + (size_t)o * (2 * kH);
  for (int h = 0; h < kH; h++) acc += xg[b * kH + h] * invg * w[h];
  for (int h = 0; h < kH; h++) acc += xacc[b * kH + h] * invn * w[kH + h];
  out[idx] = acc;
}

extern "C" void kernel_launch(void* const* d_in, const int* in_sizes, int n_in,
                              void* d_out, int out_size, void* d_ws, size_t ws_size,
                              hipStream_t stream) {
  const float* node_emb = (const float*)d_in[0];
  const float* edge_emb = (const float*)d_in[1];
  const float* lin_w = (const float*)d_in[2];
  const float* lin_b = (const float*)d_in[3];
  const float* alpha_w = (const float*)d_in[4];
  const float* alpha_b = (const float*)d_in[5];
  const float* beta_w = (const float*)d_in[6];
  const float* beta_b = (const float*)d_in[7];
  const float* wr_w = (const float*)d_in[8];
  const float* wr_b = (const float*)d_in[9];
  const float* conv_w = (const float*)d_in[10];
  const float* conv_b = (const float*)d_in[11];
  const float* mlp_w = (const float*)d_in[12];
  const float* mlp_b = (const float*)d_in[13];
  const int* visit_node = (const int*)d_in[14];
  const int* ehr_nodes = (const int*)d_in[15];
  const int* cat_node_ids = (const int*)d_in[16];
  const int* cat_edge_ids = (const int*)d_in[17];
  const int* edge_index = (const int*)d_in[18];
  const int* batch = (const int*)d_in[19];

  char* ws = (char*)d_ws;
  float* X = (float*)(ws);                            // 51,200,000
  float* ROWS = (float*)(ws + 51200000);              // 51,200,000
  float* PN = ROWS;                                   // alias (dead before ROWS used)
  float* VNT = (float*)(ws + 51200000 + 1048576);     // 3,080,192 (alias in ROWS)
  float* ZP = (float*)(ws + 56000000);                // 25,165,824 (alias in ROWS)
  float* ATTN = (float*)(ws + 102400000);             // 192,128
  float* BETA = (float*)(ws + 102592256);             // 3,840
  float* UC = (float*)(ws + 102596352);               // 1,032
  float* WREL = (float*)(ws + 102597632);             // 16,008
  int* OFF = (int*)(ws + 102613760);                  // 400,004
  int* CURSOR = (int*)(ws + 103014016);               // 400,000 (also DEG)
  int* SPART = (int*)(ws + 103414016);                // 2,048
  int* CSRS = (int*)(ws + 103416064);                 // 3,200,000
  float* CS0 = (float*)(ws + 106616064);              // 3,200,000
  float* CS1 = (float*)(ws + 109816064);              // 3,200,000
  float* XG = (float*)(ws + 113016064);               // 8,192
  int* CNT = (int*)(ws + 113024256);                  // 64
  float* XNACC = (float*)(ws + 113024320);            // 8,192
  int* CNTE = (int*)(ws + 113032512);                 // 64

  pn_kernel<<<kNV, kH, 0, stream>>>(node_emb, lin_w, lin_b, PN);
  xinit_kernel<<<(kNT * 32 + 255) / 256, 256, 0, stream>>>((const float4*)PN, cat_node_ids,
                                                           (float4*)X);
  hipMemsetAsync(XG, 0, 16512, stream);
  xnode_kernel<<<dim3(kB, 12), kH, 0, stream>>>(ehr_nodes, PN, XNACC, CNTE);
  uc_kernel<<<1, 256, 0, stream>>>(wr_w, wr_b, lin_w, lin_b, UC);
  wrel_kernel<<<(kL * kNE + 255) / 256, 256, 0, stream>>>(edge_emb, UC, WREL);
  beta_kernel<<<kL * kM, 64, 0, stream>>>(visit_node, beta_w, beta_b, BETA);
  vnt_kernel<<<dim3(kB, kKT), 256, 0, stream>>>(visit_node, VNT);
  zpart_kernel<<<dim3((kNV + 127) / 128, kB, kL * kKSZ), 256, 0, stream>>>(VNT, alpha_w, ZP);
  zsm_kernel<<<(kL * kB * kNV + 255) / 256, 256, 0, stream>>>(ZP, BETA, ATTN);

  const int* dst = edge_index + kE;
  hipMemsetAsync(CURSOR, 0, kNT * 4, stream);
  hist_kernel<<<(kE + 255) / 256, 256, 0, stream>>>(dst, CURSOR);
  scan1_kernel<<<kNB, 256, 0, stream>>>(CURSOR, OFF, SPART);
  scan2_kernel<<<1, 512, 0, stream>>>(SPART);
  scan3_kernel<<<kNB, 256, 0, stream>>>(OFF, SPART, CURSOR);
  scatter_kernel<<<(kE + 255) / 256, 256, 0, stream>>>(edge_index, cat_node_ids, cat_edge_ids,
                                                       batch, ATTN, WREL, CURSOR, CSRS, CS0, CS1);

  for (int l = 0; l < kL; l++) {
    gather_kernel<<<kNT / 8, 256, 0, stream>>>(X, CSRS, (l ? CS1 : CS0), OFF, CURSOR, ROWS);
    conv_kernel<<<(kNT + 127) / 128, 256, 0, stream>>>(ROWS, conv_w + (size_t)l * kH * kD,
                                                       conv_b + (size_t)l * kH, X);
  }

  pool_kernel<<<(kNT + 255) / 256, kH, 0, stream>>>(X, batch, XG, CNT);
  final_kernel<<<2, 256, 0, stream>>>(XG, CNT, XNACC, CNTE, mlp_w, mlp_b, (float*)d_out);
}